// Round 4
// baseline (145.119 us; speedup 1.0000x reference)
//
#include <hip/hip_runtime.h>

typedef __attribute__((ext_vector_type(8))) short short8;
typedef __attribute__((ext_vector_type(4))) float f32x4;
typedef __attribute__((ext_vector_type(4))) unsigned int u32x4;
typedef __attribute__((ext_vector_type(2))) unsigned long long u64x2;

static __device__ __forceinline__ unsigned int fbits(float f) {
    union { float f; unsigned int u; } v; v.f = f; return v.u;
}
static __device__ __forceinline__ float bitsf(unsigned int u) {
    union { float f; unsigned int u; } v; v.u = u; return v.f;
}
// pack two f32 -> bf16 pair in ONE VALU op (v_perm_b32 byte select; truncation --
// activations ~1e-4, threshold headroom is enormous)
static __device__ __forceinline__ unsigned int pkbf(float lo, float hi) {
    return __builtin_amdgcn_perm(fbits(hi), fbits(lo), 0x07060302u);
}
static __device__ __forceinline__ float bflo(unsigned int u) { return bitsf(u << 16); }
static __device__ __forceinline__ float bfhi(unsigned int u) { return bitsf(u & 0xFFFF0000u); }
// leaky = max(x, 0.01x): exact for both signs, 2 VALU ops
static __device__ __forceinline__ float leaky(float x) { return fmaxf(x, 0.01f * x); }
// 1/sqrt(x): v_rsq_f32 + one Newton step (~2^-23 rel err); validated r1-r3.
static __device__ __forceinline__ float rsqrt_nr(float x) {
    const float r = __builtin_amdgcn_rsqf(x);
    return r * (1.5f - (0.5f * x) * (r * r));
}

// STRUCTURE = round-3 (proven 53.5us) with ONE change: zbuf deleted -- phases B and
// D write IN PLACE into hbuf. Safety: every phase reads/writes only its wave's own
// 16-row stripe (wbase+16t+...); in wave64 lockstep all fragment reads issue before
// any write; the gate column i15 is lane-private (reader==writer lane for each gate
// word); interleaved epilogue read g_r / write r' collide only if r-r'=4(q-q'),
// impossible for r,r' in [0,4). LDS ops of one wave complete in order, and
// __syncthreads() still separates phases. LDS: 36864 -> 18432 B => 8 blocks/CU
// (32 waves/CU, 2x occupancy) -- this is the round-3 latency-floor fix.
//
// LDS row layout: 32 bf16 per row, k-interleaved -- u32 index c holds k=c in lo16,
// k=c+16 in hi16 (matches the HW 16x16x32 fragment layout). Row stride 9 u64
// (72 B -> max 2-way bank aliasing = free). Same k-permutation applied to the B
// (weight) fragments, so the MFMA contraction is consistent.

__global__ __launch_bounds__(256, 8) void aero_mfma(
    const float* __restrict__ vin, const float* __restrict__ win,
    const float* __restrict__ gW1, const float* __restrict__ gb1,
    const float* __restrict__ gW2, const float* __restrict__ gb2,
    const float* __restrict__ gWd1, const float* __restrict__ gbd1,
    const float* __restrict__ gWd2, const float* __restrict__ gbd2,
    const float* __restrict__ gbias,
    float* __restrict__ out, int nrows)
{
    __shared__ unsigned long long hbuf[256 * 9];  // h1 -> h2 -> z3 (in place)
    unsigned int* const h32 = (unsigned int*)hbuf;

    const int tid = threadIdx.x;
    int row = blockIdx.x * 256 + tid;
    if (row >= nrows) row = nrows - 1;   // benign duplicate work; keeps barriers uniform

    const int i15   = tid & 15;          // n within n-tile / m within m-tile
    const int quad  = (tid >> 4) & 3;    // k-chunk selector
    const int wbase = tid & 192;         // this wave's 64-row LDS window

    // ---- per-lane B fragments (weights, k-permuted) + bias for both MFMA layers ----
    unsigned int bw2[2][4], bwd1[2][4];
    float b2v[2], bd1v[2];
    #pragma unroll
    for (int u = 0; u < 2; ++u) {
        const int n = u * 16 + i15;
        const float* p2 = gW2  + n * 32 + 4 * quad;
        const float* p3 = gWd1 + n * 32 + 4 * quad;
        #pragma unroll
        for (int j = 0; j < 4; ++j) {
            bw2[u][j]  = pkbf(p2[j], p2[j + 16]);   // bf16 pair (k=4q+j, k=4q+j+16)
            bwd1[u][j] = pkbf(p3[j], p3[j + 16]);
        }
        b2v[u]  = gb2[n];
        bd1v[u] = gbd1[n];
    }

    // ---- phase A: Gram-Schmidt + layer 1 (per-lane, lane = row) ----
    const float v0 = vin[3 * row + 0], v1 = vin[3 * row + 1], v2 = vin[3 * row + 2];
    const float w0 = win[3 * row + 0], w1 = win[3 * row + 1], w2 = win[3 * row + 2];

    const float sv  = v0 * v0 + v1 * v1 + v2 * v2;
    const float rnv = rsqrt_nr(sv);
    const float a0 = v0 * rnv, a1 = v1 * rnv, a2 = v2 * rnv;       // v_on
    const float proj = w0 * a0 + w1 * a1 + w2 * a2;
    const float o0 = w0 - proj * a0, o1 = w1 - proj * a1, o2 = w2 - proj * a2;
    const float sw  = o0 * o0 + o1 * o1 + o2 * o2;
    const float rnw = rsqrt_nr(sw);
    const float c0 = o0 * rnw, c1 = o1 * rnw, c2 = o2 * rnw;       // w_on
    const float u0 = a1 * c2 - a2 * c1;                            // u_on
    const float u1 = a2 * c0 - a0 * c2;
    const float u2 = a0 * c1 - a1 * c0;

    const float f0 = sv * rnv;     // v.v_on = |v|
    const float f1 = proj;         // w.v_on
    const float f2 = sw * rnw;     // w.w_on = |w_orth|

    float h1[32];
    #pragma unroll
    for (int j = 0; j < 32; ++j) {
        float acc = gb1[j];
        acc = fmaf(gW1[3 * j + 0], f0, acc);
        acc = fmaf(gW1[3 * j + 1], f1, acc);
        acc = fmaf(gW1[3 * j + 2], f2, acc);
        h1[j] = leaky(acc);
    }

    // pack h1 (k-interleaved) and write this lane's row
    {
        unsigned long long* dst = hbuf + tid * 9;
        #pragma unroll
        for (int c2 = 0; c2 < 8; ++c2) {
            const unsigned int lo = pkbf(h1[2 * c2],     h1[2 * c2 + 16]);
            const unsigned int hi = pkbf(h1[2 * c2 + 1], h1[2 * c2 + 17]);
            dst[c2] = (unsigned long long)lo | ((unsigned long long)hi << 32);
        }
    }

    // ---- phase B: layer 2 MFMA + FUSED leaky+gate (h2 = leaky(z2)*h1), IN PLACE ----
    __syncthreads();
    {
        const short8 bf0 = __builtin_bit_cast(short8, (u32x4){bw2[0][0], bw2[0][1], bw2[0][2], bw2[0][3]});
        const short8 bf1 = __builtin_bit_cast(short8, (u32x4){bw2[1][0], bw2[1][1], bw2[1][2], bw2[1][3]});
        const f32x4 cb0 = {b2v[0], b2v[0], b2v[0], b2v[0]};
        const f32x4 cb1 = {b2v[1], b2v[1], b2v[1], b2v[1]};
        #pragma unroll
        for (int t = 0; t < 4; ++t) {
            const int ra = wbase + 16 * t + i15;
            u64x2 av;
            av.x = hbuf[ra * 9 + 2 * quad];
            av.y = hbuf[ra * 9 + 2 * quad + 1];
            const short8 af = __builtin_bit_cast(short8, av);
            const f32x4 acc0 = __builtin_amdgcn_mfma_f32_16x16x32_bf16(af, bf0, cb0, 0, 0, 0);
            const f32x4 acc1 = __builtin_amdgcn_mfma_f32_16x16x32_bf16(af, bf1, cb1, 0, 0, 0);
            const int zr = wbase + 16 * t + 4 * quad;
            #pragma unroll
            for (int r = 0; r < 4; ++r) {
                const unsigned int g = h32[(zr + r) * 18 + i15];   // h1 pair (i15, i15+16)
                h32[(zr + r) * 18 + i15] =
                    pkbf(leaky(acc0[r]) * bflo(g), leaky(acc1[r]) * bfhi(g));
            }
        }
    }

    // ---- phase D: layer 3 as MFMA (z3 = h2 @ Wd1^T + bd1), IN PLACE ----
    __syncthreads();
    {
        const short8 bf0 = __builtin_bit_cast(short8, (u32x4){bwd1[0][0], bwd1[0][1], bwd1[0][2], bwd1[0][3]});
        const short8 bf1 = __builtin_bit_cast(short8, (u32x4){bwd1[1][0], bwd1[1][1], bwd1[1][2], bwd1[1][3]});
        const f32x4 cb0 = {bd1v[0], bd1v[0], bd1v[0], bd1v[0]};
        const f32x4 cb1 = {bd1v[1], bd1v[1], bd1v[1], bd1v[1]};
        #pragma unroll
        for (int t = 0; t < 4; ++t) {
            const int ra = wbase + 16 * t + i15;
            u64x2 av;
            av.x = hbuf[ra * 9 + 2 * quad];
            av.y = hbuf[ra * 9 + 2 * quad + 1];
            const short8 af = __builtin_bit_cast(short8, av);
            const f32x4 acc0 = __builtin_amdgcn_mfma_f32_16x16x32_bf16(af, bf0, cb0, 0, 0, 0);
            const f32x4 acc1 = __builtin_amdgcn_mfma_f32_16x16x32_bf16(af, bf1, cb1, 0, 0, 0);
            const int zr = wbase + 16 * t + 4 * quad;
            #pragma unroll
            for (int r = 0; r < 4; ++r)
                h32[(zr + r) * 18 + i15] = pkbf(acc0[r], acc1[r]);
        }
    }

    // ---- phase E: leaky(z3) per-lane, layer 4 (32->3, scalar weights), rotate, store ----
    __syncthreads();
    {
        const unsigned long long* src = hbuf + tid * 9;
        float h3[32];
        #pragma unroll
        for (int c2 = 0; c2 < 8; ++c2) {
            const unsigned long long zz = src[c2];
            const unsigned int ulo = (unsigned int)zz;
            const unsigned int uhi = (unsigned int)(zz >> 32);
            h3[2 * c2]      = leaky(bflo(ulo));
            h3[2 * c2 + 16] = leaky(bfhi(ulo));
            h3[2 * c2 + 1]  = leaky(bflo(uhi));
            h3[2 * c2 + 17] = leaky(bfhi(uhi));
        }

        float y0 = gbd2[0], y1 = gbd2[1], y2 = gbd2[2];
        #pragma unroll
        for (int k = 0; k < 32; ++k) {
            y0 = fmaf(gWd2[0 * 32 + k], h3[k], y0);
            y1 = fmaf(gWd2[1 * 32 + k], h3[k], y1);
            y2 = fmaf(gWd2[2 * 32 + k], h3[k], y2);
        }

        out[3 * row + 0] = fmaf(a0, y0, fmaf(c0, y1, fmaf(u0, y2, gbias[0])));
        out[3 * row + 1] = fmaf(a1, y0, fmaf(c1, y1, fmaf(u1, y2, gbias[1])));
        out[3 * row + 2] = fmaf(a2, y0, fmaf(c2, y1, fmaf(u2, y2, gbias[2])));
    }
}

extern "C" void kernel_launch(void* const* d_in, const int* in_sizes, int n_in,
                              void* d_out, int out_size, void* d_ws, size_t ws_size,
                              hipStream_t stream) {
    const float* v    = (const float*)d_in[0];
    const float* w    = (const float*)d_in[1];
    const float* W1   = (const float*)d_in[2];
    const float* b1   = (const float*)d_in[3];
    const float* W2   = (const float*)d_in[4];
    const float* b2   = (const float*)d_in[5];
    const float* Wd1  = (const float*)d_in[6];
    const float* bd1  = (const float*)d_in[7];
    const float* Wd2  = (const float*)d_in[8];
    const float* bd2  = (const float*)d_in[9];
    const float* bias = (const float*)d_in[10];

    const int nrows = in_sizes[0] / 3;
    dim3 block(256);
    dim3 grid((nrows + 255) / 256);
    hipLaunchKernelGGL(aero_mfma, grid, block, 0, stream,
                       v, w, W1, b1, W2, b2, Wd1, bd1, Wd2, bd2, bias,
                       (float*)d_out, nrows);
}

// Round 5
// 141.388 us; speedup vs baseline: 1.0264x; 1.0264x over previous
//
#include <hip/hip_runtime.h>

typedef __attribute__((ext_vector_type(8))) short short8;
typedef __attribute__((ext_vector_type(4))) float f32x4;
typedef __attribute__((ext_vector_type(4))) unsigned int u32x4;
typedef __attribute__((ext_vector_type(2))) unsigned long long u64x2;

static __device__ __forceinline__ unsigned int fbits(float f) {
    union { float f; unsigned int u; } v; v.f = f; return v.u;
}
static __device__ __forceinline__ float bitsf(unsigned int u) {
    union { float f; unsigned int u; } v; v.u = u; return v.f;
}
// pack two f32 -> bf16 pair in ONE VALU op (v_perm_b32 byte select; truncation --
// activations ~1e-4, threshold headroom is enormous)
static __device__ __forceinline__ unsigned int pkbf(float lo, float hi) {
    return __builtin_amdgcn_perm(fbits(hi), fbits(lo), 0x07060302u);
}
static __device__ __forceinline__ float bflo(unsigned int u) { return bitsf(u << 16); }
static __device__ __forceinline__ float bfhi(unsigned int u) { return bitsf(u & 0xFFFF0000u); }
// leaky = max(x, 0.01x): exact for both signs, 2 VALU ops
static __device__ __forceinline__ float leaky(float x) { return fmaxf(x, 0.01f * x); }
// 1/sqrt(x): v_rsq_f32 + one Newton step (~2^-23 rel err); validated r1-r3.
static __device__ __forceinline__ float rsqrt_nr(float x) {
    const float r = __builtin_amdgcn_rsqf(x);
    return r * (1.5f - (0.5f * x) * (r * r));
}

// STRUCTURE = round-4 (single in-place hbuf, 18432 B LDS -> 8 blocks/CU) with the
// spill bug fixed: __launch_bounds__(256, 4), NOT (256, 8). Round-4's (256,8)
// forced VGPR_Count=32, spilling the h1[32]/h3[32] arrays to scratch (WRITE_SIZE
// 24.6 -> 60.5 MB of spill traffic, VALUBusy 61%). The natural allocation for this
// code is ~52 VGPR (round 3) -> 64-granule -> 8 waves/SIMD: full 32 waves/CU
// occupancy WITHOUT forcing. LDS halving is validated (occupancy 35 -> 71%).
//
// In-place safety (round-4 analysis, unchanged): every phase reads/writes only its
// wave's own 16-row stripe (wbase+16t+...); in wave64 lockstep all fragment reads
// issue before any write; the gate word (zr+r, i15) is written by the same lane
// that read it; interleaved epilogue read g_r / write r' collide only if
// r-r'=4(q-q'), impossible for r,r' in [0,4). __syncthreads() separates phases.
//
// LDS row layout: 32 bf16 per row, k-interleaved -- u32 index c holds k=c in lo16,
// k=c+16 in hi16 (matches the HW 16x16x32 fragment layout). Row stride 9 u64
// (72 B -> max 2-way bank aliasing = free). Same k-permutation applied to the B
// (weight) fragments, so the MFMA contraction is consistent.

__global__ __launch_bounds__(256, 4) void aero_mfma(
    const float* __restrict__ vin, const float* __restrict__ win,
    const float* __restrict__ gW1, const float* __restrict__ gb1,
    const float* __restrict__ gW2, const float* __restrict__ gb2,
    const float* __restrict__ gWd1, const float* __restrict__ gbd1,
    const float* __restrict__ gWd2, const float* __restrict__ gbd2,
    const float* __restrict__ gbias,
    float* __restrict__ out, int nrows)
{
    __shared__ unsigned long long hbuf[256 * 9];  // h1 -> h2 -> z3 (in place)
    unsigned int* const h32 = (unsigned int*)hbuf;

    const int tid = threadIdx.x;
    int row = blockIdx.x * 256 + tid;
    if (row >= nrows) row = nrows - 1;   // benign duplicate work; keeps barriers uniform

    const int i15   = tid & 15;          // n within n-tile / m within m-tile
    const int quad  = (tid >> 4) & 3;    // k-chunk selector
    const int wbase = tid & 192;         // this wave's 64-row LDS window

    // ---- per-lane B fragments (weights, k-permuted) + bias for both MFMA layers ----
    unsigned int bw2[2][4], bwd1[2][4];
    float b2v[2], bd1v[2];
    #pragma unroll
    for (int u = 0; u < 2; ++u) {
        const int n = u * 16 + i15;
        const float* p2 = gW2  + n * 32 + 4 * quad;
        const float* p3 = gWd1 + n * 32 + 4 * quad;
        #pragma unroll
        for (int j = 0; j < 4; ++j) {
            bw2[u][j]  = pkbf(p2[j], p2[j + 16]);   // bf16 pair (k=4q+j, k=4q+j+16)
            bwd1[u][j] = pkbf(p3[j], p3[j + 16]);
        }
        b2v[u]  = gb2[n];
        bd1v[u] = gbd1[n];
    }

    // ---- phase A: Gram-Schmidt + layer 1 (per-lane, lane = row) ----
    const float v0 = vin[3 * row + 0], v1 = vin[3 * row + 1], v2 = vin[3 * row + 2];
    const float w0 = win[3 * row + 0], w1 = win[3 * row + 1], w2 = win[3 * row + 2];

    const float sv  = v0 * v0 + v1 * v1 + v2 * v2;
    const float rnv = rsqrt_nr(sv);
    const float a0 = v0 * rnv, a1 = v1 * rnv, a2 = v2 * rnv;       // v_on
    const float proj = w0 * a0 + w1 * a1 + w2 * a2;
    const float o0 = w0 - proj * a0, o1 = w1 - proj * a1, o2 = w2 - proj * a2;
    const float sw  = o0 * o0 + o1 * o1 + o2 * o2;
    const float rnw = rsqrt_nr(sw);
    const float c0 = o0 * rnw, c1 = o1 * rnw, c2 = o2 * rnw;       // w_on
    const float u0 = a1 * c2 - a2 * c1;                            // u_on
    const float u1 = a2 * c0 - a0 * c2;
    const float u2 = a0 * c1 - a1 * c0;

    const float f0 = sv * rnv;     // v.v_on = |v|
    const float f1 = proj;         // w.v_on
    const float f2 = sw * rnw;     // w.w_on = |w_orth|

    float h1[32];
    #pragma unroll
    for (int j = 0; j < 32; ++j) {
        float acc = gb1[j];
        acc = fmaf(gW1[3 * j + 0], f0, acc);
        acc = fmaf(gW1[3 * j + 1], f1, acc);
        acc = fmaf(gW1[3 * j + 2], f2, acc);
        h1[j] = leaky(acc);
    }

    // pack h1 (k-interleaved) and write this lane's row
    {
        unsigned long long* dst = hbuf + tid * 9;
        #pragma unroll
        for (int c2 = 0; c2 < 8; ++c2) {
            const unsigned int lo = pkbf(h1[2 * c2],     h1[2 * c2 + 16]);
            const unsigned int hi = pkbf(h1[2 * c2 + 1], h1[2 * c2 + 17]);
            dst[c2] = (unsigned long long)lo | ((unsigned long long)hi << 32);
        }
    }

    // ---- phase B: layer 2 MFMA + FUSED leaky+gate (h2 = leaky(z2)*h1), IN PLACE ----
    __syncthreads();
    {
        const short8 bf0 = __builtin_bit_cast(short8, (u32x4){bw2[0][0], bw2[0][1], bw2[0][2], bw2[0][3]});
        const short8 bf1 = __builtin_bit_cast(short8, (u32x4){bw2[1][0], bw2[1][1], bw2[1][2], bw2[1][3]});
        const f32x4 cb0 = {b2v[0], b2v[0], b2v[0], b2v[0]};
        const f32x4 cb1 = {b2v[1], b2v[1], b2v[1], b2v[1]};
        #pragma unroll
        for (int t = 0; t < 4; ++t) {
            const int ra = wbase + 16 * t + i15;
            u64x2 av;
            av.x = hbuf[ra * 9 + 2 * quad];
            av.y = hbuf[ra * 9 + 2 * quad + 1];
            const short8 af = __builtin_bit_cast(short8, av);
            const f32x4 acc0 = __builtin_amdgcn_mfma_f32_16x16x32_bf16(af, bf0, cb0, 0, 0, 0);
            const f32x4 acc1 = __builtin_amdgcn_mfma_f32_16x16x32_bf16(af, bf1, cb1, 0, 0, 0);
            const int zr = wbase + 16 * t + 4 * quad;
            #pragma unroll
            for (int r = 0; r < 4; ++r) {
                const unsigned int g = h32[(zr + r) * 18 + i15];   // h1 pair (i15, i15+16)
                h32[(zr + r) * 18 + i15] =
                    pkbf(leaky(acc0[r]) * bflo(g), leaky(acc1[r]) * bfhi(g));
            }
        }
    }

    // ---- phase D: layer 3 as MFMA (z3 = h2 @ Wd1^T + bd1), IN PLACE ----
    __syncthreads();
    {
        const short8 bf0 = __builtin_bit_cast(short8, (u32x4){bwd1[0][0], bwd1[0][1], bwd1[0][2], bwd1[0][3]});
        const short8 bf1 = __builtin_bit_cast(short8, (u32x4){bwd1[1][0], bwd1[1][1], bwd1[1][2], bwd1[1][3]});
        const f32x4 cb0 = {bd1v[0], bd1v[0], bd1v[0], bd1v[0]};
        const f32x4 cb1 = {bd1v[1], bd1v[1], bd1v[1], bd1v[1]};
        #pragma unroll
        for (int t = 0; t < 4; ++t) {
            const int ra = wbase + 16 * t + i15;
            u64x2 av;
            av.x = hbuf[ra * 9 + 2 * quad];
            av.y = hbuf[ra * 9 + 2 * quad + 1];
            const short8 af = __builtin_bit_cast(short8, av);
            const f32x4 acc0 = __builtin_amdgcn_mfma_f32_16x16x32_bf16(af, bf0, cb0, 0, 0, 0);
            const f32x4 acc1 = __builtin_amdgcn_mfma_f32_16x16x32_bf16(af, bf1, cb1, 0, 0, 0);
            const int zr = wbase + 16 * t + 4 * quad;
            #pragma unroll
            for (int r = 0; r < 4; ++r)
                h32[(zr + r) * 18 + i15] = pkbf(acc0[r], acc1[r]);
        }
    }

    // ---- phase E: leaky(z3) per-lane, layer 4 (32->3, scalar weights), rotate, store ----
    __syncthreads();
    {
        const unsigned long long* src = hbuf + tid * 9;
        float h3[32];
        #pragma unroll
        for (int c2 = 0; c2 < 8; ++c2) {
            const unsigned long long zz = src[c2];
            const unsigned int ulo = (unsigned int)zz;
            const unsigned int uhi = (unsigned int)(zz >> 32);
            h3[2 * c2]      = leaky(bflo(ulo));
            h3[2 * c2 + 16] = leaky(bfhi(ulo));
            h3[2 * c2 + 1]  = leaky(bflo(uhi));
            h3[2 * c2 + 17] = leaky(bfhi(uhi));
        }

        float y0 = gbd2[0], y1 = gbd2[1], y2 = gbd2[2];
        #pragma unroll
        for (int k = 0; k < 32; ++k) {
            y0 = fmaf(gWd2[0 * 32 + k], h3[k], y0);
            y1 = fmaf(gWd2[1 * 32 + k], h3[k], y1);
            y2 = fmaf(gWd2[2 * 32 + k], h3[k], y2);
        }

        out[3 * row + 0] = fmaf(a0, y0, fmaf(c0, y1, fmaf(u0, y2, gbias[0])));
        out[3 * row + 1] = fmaf(a1, y0, fmaf(c1, y1, fmaf(u1, y2, gbias[1])));
        out[3 * row + 2] = fmaf(a2, y0, fmaf(c2, y1, fmaf(u2, y2, gbias[2])));
    }
}

extern "C" void kernel_launch(void* const* d_in, const int* in_sizes, int n_in,
                              void* d_out, int out_size, void* d_ws, size_t ws_size,
                              hipStream_t stream) {
    const float* v    = (const float*)d_in[0];
    const float* w    = (const float*)d_in[1];
    const float* W1   = (const float*)d_in[2];
    const float* b1   = (const float*)d_in[3];
    const float* W2   = (const float*)d_in[4];
    const float* b2   = (const float*)d_in[5];
    const float* Wd1  = (const float*)d_in[6];
    const float* bd1  = (const float*)d_in[7];
    const float* Wd2  = (const float*)d_in[8];
    const float* bd2  = (const float*)d_in[9];
    const float* bias = (const float*)d_in[10];

    const int nrows = in_sizes[0] / 3;
    dim3 block(256);
    dim3 grid((nrows + 255) / 256);
    hipLaunchKernelGGL(aero_mfma, grid, block, 0, stream,
                       v, w, W1, b1, W2, b2, Wd1, bd1, Wd2, bd2, bias,
                       (float*)d_out, nrows);
}